// Round 12
// baseline (211.728 us; speedup 1.0000x reference)
//
#include <hip/hip_runtime.h>
#include <hip/hip_bf16.h>

namespace {
constexpr int N = 16384;
constexpr int K = 2048;
constexpr int D = 1000;
constexpr int RB = 512;            // fp4 row bytes (1024 elems * 0.5 B)
constexpr size_t ND = (size_t)N * D;
constexpr float WSCALE4 = 8192.0f; // codebook pre-scale: |w|max*8192 = 4.0 (fp4 grid top 6)

// workspace layout
constexpr size_t OFF_BEST   = 0;                               // N * u64
constexpr size_t OFF_COUNTS = OFF_BEST + (size_t)N * 8;        // K * u32
constexpr size_t HDR_BYTES  = OFF_COUNTS + (size_t)K * 4;      // zeroed by init_kernel
constexpr size_t OFF_PART   = HDR_BYTES;                       // 2048*2 f32
constexpr size_t OFF_XQ     = OFF_PART + 2048 * 2 * 4;         // N*RB fp4
constexpr size_t OFF_WQ     = OFF_XQ + (size_t)N * RB;         // K*RB fp4
constexpr size_t OFF_WNORM  = OFF_WQ + (size_t)K * RB;         // K f32
}

typedef __attribute__((ext_vector_type(8))) int int8v;
typedef __attribute__((ext_vector_type(4))) int int4v;
typedef __attribute__((ext_vector_type(16))) float f32x16;

typedef const __attribute__((address_space(1))) unsigned int* gp_t;
typedef __attribute__((address_space(3))) unsigned int* lp_t;

// zero best[] + counts[] (139264 B = 34 blocks * 256 threads * 16 B)
__global__ __launch_bounds__(256) void init_kernel(uint4* __restrict__ p) {
  p[blockIdx.x * 256 + threadIdx.x] = make_uint4(0u, 0u, 0u, 0u);
}

// fp4 e2m1 encode: grid {0,.5,1,1.5,2,3,4,6}, RTE thresholds
__device__ inline unsigned int fp4nib(float v) {
  float u = fabsf(v);
  unsigned int s = (__float_as_uint(v) >> 28) & 8u;   // sign -> bit 3
  unsigned int c = (u >= 0.25f) + (u >= 0.75f) + (u >= 1.25f) + (u >= 1.75f)
                 + (u >= 2.5f) + (u >= 3.5f) + (u >= 5.0f);
  return s | c;
}

// fp32 [rows][1000] -> fp4 e2m1 [rows][1024] (zero padded), optional pre-scale
__global__ __launch_bounds__(256) void conv_fp4_kernel(const float* __restrict__ src,
                                                       unsigned int* __restrict__ dst,
                                                       int nrows, float scale) {
  int t = blockIdx.x * 256 + threadIdx.x;
  int r = t >> 7;          // 128 uints (8 elems each) per row
  int c = t & 127;
  if (r >= nrows) return;
  unsigned int out = 0;
  if (c < 125) {           // 125*8 = 1000 exactly
    const float* p = src + (size_t)r * D + (c << 3);
    float4 v0 = *reinterpret_cast<const float4*>(p);
    float4 v1 = *reinterpret_cast<const float4*>(p + 4);
    out  = fp4nib(v0.x * scale);
    out |= fp4nib(v0.y * scale) << 4;
    out |= fp4nib(v0.z * scale) << 8;
    out |= fp4nib(v0.w * scale) << 12;
    out |= fp4nib(v1.x * scale) << 16;
    out |= fp4nib(v1.y * scale) << 20;
    out |= fp4nib(v1.z * scale) << 24;
    out |= fp4nib(v1.w * scale) << 28;
  }
  dst[(size_t)r * 128 + c] = out;
}

// |w_k|^2 in fp32 from the original embedding; one wave per row
__global__ __launch_bounds__(256) void wnorm_kernel(const float* __restrict__ W,
                                                    float* __restrict__ wnorm) {
  int wv = (blockIdx.x * 256 + threadIdx.x) >> 6;
  int lane = threadIdx.x & 63;
  if (wv >= K) return;
  const float* p = W + (size_t)wv * D;
  float s = 0.f;
  for (int d = lane; d < D; d += 64) { float v = p[d]; s += v * v; }
  #pragma unroll
  for (int off = 32; off; off >>= 1) s += __shfl_down(s, off);
  if (lane == 0) wnorm[wv] = s;
}

__global__ __launch_bounds__(256) void hist_kernel(const int* __restrict__ label,
                                                   unsigned int* __restrict__ counts) {
  int t = blockIdx.x * 256 + threadIdx.x;
  if (t < N) atomicAdd(&counts[label[t]], 1u);
}

// encodings = one_hot(label); float2 stores (base offset is only 8B-aligned)
__global__ __launch_bounds__(256) void encodings_kernel(const int* __restrict__ label,
                                                        float2* __restrict__ enc) {
  size_t t = (size_t)blockIdx.x * 256 + threadIdx.x;   // N*K/2 threads
  int row = (int)(t >> 10);                            // K/2 = 1024 float2 per row
  int c2 = (int)(t & 1023);
  int lab = label[row];
  float2 v = make_float2(0.f, 0.f);
  if ((lab >> 1) == c2) { if (lab & 1) v.y = 1.f; else v.x = 1.f; }
  enc[t] = v;
}

// Reoriented argmin: D = Wq4 . Xq4^T via MX-fp4 32x32x64 MFMA (FMT=4: e2m1).
// Identical to R10's production kernel. THIS ROUND: dispatched 4x (idempotent
// atomicMax) purely so it surfaces in rocprof top-5 with full counters.
__global__ __launch_bounds__(512, 1) void argmin_kernel(const unsigned char* __restrict__ Xq,
                                                        const unsigned char* __restrict__ Wq,
                                                        const float* __restrict__ wnorm,
                                                        unsigned long long* __restrict__ best) {
  constexpr int BUFB = 49152;   // A 32 KB (256 rows x 128 B) + B 16 KB (128 x 128 B)
  __shared__ __attribute__((aligned(16))) unsigned char smem[151552];

  const int tid = threadIdx.x;
  const int bid = blockIdx.x;
  const int w = tid >> 6, l = tid & 63;
  const int wr = w >> 1;               // wave's code quarter of BM (0..3)
  const int wx = w & 1;                // wave's sample half (0,1)
  const int lc = l & 31;               // frag row / C-D col
  const int lh = l >> 5;               // k-half selector
  const int w0 = (bid & 1) * 1024;     // code-half base
  const int x0 = (bid >> 1) * 128;     // sample-panel base

  const int srow = tid >> 3;           // 0..63
  const int schunk = ((tid & 7) ^ (srow & 7)) << 4;
  auto lsm = (__attribute__((address_space(3))) unsigned char*)smem;
  const float* wsm = (const float*)(smem + 147456);

  const int sxo = lc & 7;
  int chv[4];
  #pragma unroll
  for (int tau = 0; tau < 4; ++tau) chv[tau] = (((2 * tau + lh) ^ sxo) << 4);
  int arow[2], brow[2];
  #pragma unroll
  for (int m = 0; m < 2; ++m) {
    arow[m] = (wr * 64 + m * 32 + lc) * 128;            // A: 256 rows x 128 B
    brow[m] = (wx * 64 + m * 32 + lc) * 128 + 32768;    // B: 128 rows x 128 B
  }

#define STAGE(Tn, _b) do {                                                               \
    const unsigned char* _gA = Wq + (size_t)(w0 + ((Tn) >> 2) * 256 + srow) * RB         \
                               + ((Tn) & 3) * 128 + schunk;                              \
    const unsigned char* _gB = Xq + (size_t)(x0 + srow) * RB                             \
                               + ((Tn) & 3) * 128 + schunk;                              \
    _Pragma("unroll")                                                                    \
    for (int _i = 0; _i < 4; ++_i)                                                       \
      __builtin_amdgcn_global_load_lds((gp_t)(_gA + (size_t)(64 * _i) * RB),             \
                                       (lp_t)(lsm + (_b) + _i * 8192 + tid * 16), 16, 0, 0);\
    _Pragma("unroll")                                                                    \
    for (int _i = 0; _i < 2; ++_i)                                                       \
      __builtin_amdgcn_global_load_lds((gp_t)(_gB + (size_t)(64 * _i) * RB),             \
                                       (lp_t)(lsm + (_b) + 32768 + _i * 8192 + tid * 16), 16, 0, 0);\
  } while (0)

#define KBODY(bufb) do {                                                                 \
    _Pragma("unroll")                                                                    \
    for (int tau = 0; tau < 4; ++tau) {                                                  \
      int4v la0 = *reinterpret_cast<const int4v*>(smem + (bufb) + arow[0] + chv[tau]);   \
      int4v la1 = *reinterpret_cast<const int4v*>(smem + (bufb) + arow[1] + chv[tau]);   \
      int4v lb0 = *reinterpret_cast<const int4v*>(smem + (bufb) + brow[0] + chv[tau]);   \
      int4v lb1 = *reinterpret_cast<const int4v*>(smem + (bufb) + brow[1] + chv[tau]);   \
      int8v a0, a1, b0, b1;                                                              \
      a0[0]=la0[0];a0[1]=la0[1];a0[2]=la0[2];a0[3]=la0[3];                               \
      a0[4]=la0[0];a0[5]=la0[1];a0[6]=la0[2];a0[7]=la0[3];                               \
      a1[0]=la1[0];a1[1]=la1[1];a1[2]=la1[2];a1[3]=la1[3];                               \
      a1[4]=la1[0];a1[5]=la1[1];a1[6]=la1[2];a1[7]=la1[3];                               \
      b0[0]=lb0[0];b0[1]=lb0[1];b0[2]=lb0[2];b0[3]=lb0[3];                               \
      b0[4]=lb0[0];b0[5]=lb0[1];b0[6]=lb0[2];b0[7]=lb0[3];                               \
      b1[0]=lb1[0];b1[1]=lb1[1];b1[2]=lb1[2];b1[3]=lb1[3];                               \
      b1[4]=lb1[0];b1[5]=lb1[1];b1[6]=lb1[2];b1[7]=lb1[3];                               \
      __builtin_amdgcn_s_setprio(1);                                                     \
      acc[0][0] = __builtin_amdgcn_mfma_scale_f32_32x32x64_f8f6f4(a0, b0, acc[0][0], 4, 4, 0, 0x7f7f7f7f, 0, 0x7f7f7f7f); \
      acc[0][1] = __builtin_amdgcn_mfma_scale_f32_32x32x64_f8f6f4(a0, b1, acc[0][1], 4, 4, 0, 0x7f7f7f7f, 0, 0x7f7f7f7f); \
      acc[1][0] = __builtin_amdgcn_mfma_scale_f32_32x32x64_f8f6f4(a1, b0, acc[1][0], 4, 4, 0, 0x7f7f7f7f, 0, 0x7f7f7f7f); \
      acc[1][1] = __builtin_amdgcn_mfma_scale_f32_32x32x64_f8f6f4(a1, b1, acc[1][1], 4, 4, 0, 0x7f7f7f7f, 0, 0x7f7f7f7f); \
      __builtin_amdgcn_s_setprio(0);                                                     \
    }                                                                                    \
  } while (0)

#define FOLD(ct_) do {                                                                   \
    _Pragma("unroll")                                                                    \
    for (int m = 0; m < 2; ++m) {                                                        \
      _Pragma("unroll")                                                                  \
      for (int r = 0; r < 16; ++r) {                                                     \
        const int wl = wr * 64 + m * 32 + (r & 3) + 8 * (r >> 2) + 4 * lh;               \
        const float wn = wsm[(ct_) * 256 + wl];                                          \
        const unsigned int nw = ~(unsigned int)(w0 + (ct_) * 256 + wl);                  \
        float s0 = dsc * acc[m][0][r] - wn;                                              \
        float s1 = dsc * acc[m][1][r] - wn;                                              \
        unsigned int u0 = __float_as_uint(s0);                                           \
        u0 = (u0 & 0x80000000u) ? ~u0 : (u0 | 0x80000000u);                              \
        unsigned int u1 = __float_as_uint(s1);                                           \
        u1 = (u1 & 0x80000000u) ? ~u1 : (u1 | 0x80000000u);                              \
        unsigned long long p0 = ((unsigned long long)u0 << 32) | nw;                     \
        unsigned long long p1 = ((unsigned long long)u1 << 32) | nw;                     \
        if (p0 > best0) best0 = p0;                                                      \
        if (p1 > best1) best1 = p1;                                                      \
        acc[m][0][r] = 0.f;                                                              \
        acc[m][1][r] = 0.f;                                                              \
      }                                                                                  \
    }                                                                                    \
  } while (0)

  f32x16 acc[2][2];
  #pragma unroll
  for (int m = 0; m < 2; ++m)
    #pragma unroll
    for (int n = 0; n < 2; ++n)
      #pragma unroll
      for (int r = 0; r < 16; ++r) acc[m][n][r] = 0.f;

  const float dsc = 2.0f / WSCALE4;
  unsigned long long best0 = 0ull, best1 = 0ull;

  // prologue: wsm (2 loads FIRST so step-0's vmcnt(6) covers them), then T=0, T=1
  __builtin_amdgcn_global_load_lds((gp_t)(wnorm + w0 + tid),
                                   (lp_t)(lsm + 147456 + tid * 4), 4, 0, 0);
  __builtin_amdgcn_global_load_lds((gp_t)(wnorm + w0 + 512 + tid),
                                   (lp_t)(lsm + 147456 + 2048 + tid * 4), 4, 0, 0);
  STAGE(0, 0);
  STAGE(1, BUFB);

  int bufb = 0;            // buffer of macro-step T
  int sb = 2 * BUFB;       // buffer for STAGE(T+2)
  for (int T = 0; T < 15; ++T) {
    asm volatile("s_waitcnt vmcnt(6)" ::: "memory");
    __builtin_amdgcn_s_barrier();                     // all waves' stage(T) landed
    __builtin_amdgcn_sched_barrier(0);                // nothing crosses the barrier
    if (T + 2 < 16) STAGE(T + 2, sb);                 // overwrites buf(T-1): readers passed barrier
    KBODY(bufb);
    if ((T & 3) == 3) FOLD(T >> 2);
    bufb = (bufb == 2 * BUFB) ? 0 : bufb + BUFB;
    sb = (sb == 2 * BUFB) ? 0 : sb + BUFB;
  }
  {  // peeled last macro-step: drain fully
    asm volatile("s_waitcnt vmcnt(0)" ::: "memory");
    __builtin_amdgcn_s_barrier();
    __builtin_amdgcn_sched_barrier(0);
    KBODY(bufb);
    FOLD(3);
  }
#undef STAGE
#undef KBODY
#undef FOLD

  // merge lane-halves (same sample, different code rows), one atomic per sample
  unsigned long long o0 = __shfl_xor(best0, 32);
  if (o0 > best0) best0 = o0;
  unsigned long long o1 = __shfl_xor(best1, 32);
  if (o1 > best1) best1 = o1;
  if (lh == 0) {
    atomicMax(best + x0 + wx * 64 + lc, best0);
    atomicMax(best + x0 + wx * 64 + 32 + lc, best1);
  }
}

// gather quantized rows, write straight-through output, per-block partial sums (NO atomics)
__global__ __launch_bounds__(256) void gather_loss_kernel(const float* __restrict__ X,
                                                          const float* __restrict__ W,
                                                          const int* __restrict__ label,
                                                          const unsigned long long* __restrict__ best,
                                                          float* __restrict__ outq,
                                                          float* __restrict__ partials) {
  const int tid = threadIdx.x;
  float qs = 0.f, xs = 0.f;
  #pragma unroll
  for (int i = 0; i < 8; ++i) {
    const int r = blockIdx.x * 8 + i;
    const int lab = label[r];
    const int k = (int)(~(unsigned int)(best[r] & 0xffffffffull));
    const float ind = (lab != k) ? 1.0f : 0.0f;
    if (tid < 250) {
      const float4 x4 = reinterpret_cast<const float4*>(X + (size_t)r * D)[tid];
      const float4 q4 = reinterpret_cast<const float4*>(W + (size_t)lab * D)[tid];
      const float4 c4 = reinterpret_cast<const float4*>(W + (size_t)k * D)[tid];
      float* orow = outq + (size_t)r * D + tid * 4;
      orow[0] = x4.x + (q4.x - x4.x);
      orow[1] = x4.y + (q4.y - x4.y);
      orow[2] = x4.z + (q4.z - x4.z);
      orow[3] = x4.w + (q4.w - x4.w);
      float dq, dc, rx = 0.f, rq = 0.f;
      dq = q4.x - x4.x; rq += dq * dq;  dq = q4.y - x4.y; rq += dq * dq;
      dq = q4.z - x4.z; rq += dq * dq;  dq = q4.w - x4.w; rq += dq * dq;
      dc = c4.x - x4.x; rx += dc * dc;  dc = c4.y - x4.y; rx += dc * dc;
      dc = c4.z - x4.z; rx += dc * dc;  dc = c4.w - x4.w; rx += dc * dc;
      qs += rq;
      xs += ind * rx;
    }
  }
  #pragma unroll
  for (int off = 32; off; off >>= 1) {
    qs += __shfl_down(qs, off);
    xs += __shfl_down(xs, off);
  }
  __shared__ float sq[4], sx[4];
  if ((tid & 63) == 0) { sq[tid >> 6] = qs; sx[tid >> 6] = xs; }
  __syncthreads();
  if (tid == 0) {
    partials[blockIdx.x * 2 + 0] = sq[0] + sq[1] + sq[2] + sq[3];
    partials[blockIdx.x * 2 + 1] = sx[0] + sx[1] + sx[2] + sx[3];
  }
}

__global__ __launch_bounds__(256) void final_kernel(const unsigned int* __restrict__ counts,
                                                    const float* __restrict__ partials,
                                                    float* __restrict__ out) {
  const int tid = threadIdx.x;
  float e = 0.f, qs = 0.f, xs = 0.f;
  for (int k = tid; k < K; k += 256) {
    float p = (float)counts[k] * (1.0f / (float)N);
    e += p * logf(p + 1e-10f);
  }
  for (int i = tid; i < 2048; i += 256) {
    qs += partials[i * 2 + 0];
    xs += partials[i * 2 + 1];
  }
  #pragma unroll
  for (int off = 32; off; off >>= 1) {
    e += __shfl_down(e, off);
    qs += __shfl_down(qs, off);
    xs += __shfl_down(xs, off);
  }
  __shared__ float se[4], ssq[4], ssx[4];
  if ((tid & 63) == 0) { se[tid >> 6] = e; ssq[tid >> 6] = qs; ssx[tid >> 6] = xs; }
  __syncthreads();
  if (tid == 0) {
    float ent = se[0] + se[1] + se[2] + se[3];
    float q = ssq[0] + ssq[1] + ssq[2] + ssq[3];
    float x = ssx[0] + ssx[1] + ssx[2] + ssx[3];
    const float inv = 1.0f / (float)((long long)N * D);
    out[0] = 1.25f * q * inv - 1.1f * x * inv;   // loss
    out[1 + ND] = expf(-ent);                    // perplexity
  }
}

extern "C" void kernel_launch(void* const* d_in, const int* in_sizes, int n_in,
                              void* d_out, int out_size, void* d_ws, size_t ws_size,
                              hipStream_t stream) {
  const float* X = (const float*)d_in[0];
  const int* label = (const int*)d_in[1];
  const float* W = (const float*)d_in[2];
  float* out = (float*)d_out;
  char* ws = (char*)d_ws;

  unsigned long long* best = (unsigned long long*)(ws + OFF_BEST);
  unsigned int* counts = (unsigned int*)(ws + OFF_COUNTS);
  float* partials = (float*)(ws + OFF_PART);
  unsigned char* Xq = (unsigned char*)(ws + OFF_XQ);
  unsigned char* Wq = (unsigned char*)(ws + OFF_WQ);
  float* wnorm = (float*)(ws + OFF_WNORM);

  init_kernel<<<34, 256, 0, stream>>>((uint4*)ws);   // zero best+counts (139264 B)

  conv_fp4_kernel<<<(N * 128) / 256, 256, 0, stream>>>(X, (unsigned int*)Xq, N, 1.0f);
  conv_fp4_kernel<<<(K * 128) / 256, 256, 0, stream>>>(W, (unsigned int*)Wq, K, WSCALE4);
  wnorm_kernel<<<K / 4, 256, 0, stream>>>(W, wnorm);
  hist_kernel<<<N / 256, 256, 0, stream>>>(label, counts);
  encodings_kernel<<<(int)((size_t)N * K / 2 / 256), 256, 0, stream>>>(
      label, (float2*)(out + 2 + ND));
  // DIAGNOSTIC ROUND: dispatch the production argmin 4x (idempotent atomicMax;
  // best[] re-zeroed each call) so it surfaces in rocprof top-5 with full
  // counters. Next round reverts to 1x and applies the counter-directed fix.
  argmin_kernel<<<256, 512, 0, stream>>>(Xq, Wq, wnorm, best);
  argmin_kernel<<<256, 512, 0, stream>>>(Xq, Wq, wnorm, best);
  argmin_kernel<<<256, 512, 0, stream>>>(Xq, Wq, wnorm, best);
  argmin_kernel<<<256, 512, 0, stream>>>(Xq, Wq, wnorm, best);
  gather_loss_kernel<<<N / 8, 256, 0, stream>>>(X, W, label, best, out + 1, partials);
  final_kernel<<<1, 256, 0, stream>>>(counts, partials, out);
}

// Round 13
// 114.386 us; speedup vs baseline: 1.8510x; 1.8510x over previous
//
#include <hip/hip_runtime.h>
#include <hip/hip_bf16.h>

namespace {
constexpr int N = 16384;
constexpr int K = 2048;
constexpr int D = 1000;
constexpr int RB = 512;            // fp4 row bytes (1024 elems * 0.5 B)
constexpr size_t ND = (size_t)N * D;
constexpr float WSCALE4 = 8192.0f; // codebook pre-scale: |w|max*8192 = 4.0 (fp4 grid top 6)

// workspace layout
constexpr size_t OFF_BEST   = 0;                               // N * u64
constexpr size_t OFF_COUNTS = OFF_BEST + (size_t)N * 8;        // K * u32
constexpr size_t HDR_BYTES  = OFF_COUNTS + (size_t)K * 4;      // zeroed by init_kernel
constexpr size_t OFF_PART   = HDR_BYTES;                       // 2048*2 f32
constexpr size_t OFF_XQ     = OFF_PART + 2048 * 2 * 4;         // N*RB fp4
constexpr size_t OFF_WQ     = OFF_XQ + (size_t)N * RB;         // K*RB fp4
constexpr size_t OFF_WNORM  = OFF_WQ + (size_t)K * RB;         // K f32
}

typedef __attribute__((ext_vector_type(8))) int int8v;
typedef __attribute__((ext_vector_type(4))) int int4v;
typedef __attribute__((ext_vector_type(16))) float f32x16;

typedef const __attribute__((address_space(1))) unsigned int* gp_t;
typedef __attribute__((address_space(3))) unsigned int* lp_t;

// zero best[] + counts[] (139264 B = 34 blocks * 256 threads * 16 B)
__global__ __launch_bounds__(256) void init_kernel(uint4* __restrict__ p) {
  p[blockIdx.x * 256 + threadIdx.x] = make_uint4(0u, 0u, 0u, 0u);
}

// fp4 e2m1 encode: grid {0,.5,1,1.5,2,3,4,6}, RTE thresholds
__device__ inline unsigned int fp4nib(float v) {
  float u = fabsf(v);
  unsigned int s = (__float_as_uint(v) >> 28) & 8u;   // sign -> bit 3
  unsigned int c = (u >= 0.25f) + (u >= 0.75f) + (u >= 1.25f) + (u >= 1.75f)
                 + (u >= 2.5f) + (u >= 3.5f) + (u >= 5.0f);
  return s | c;
}

// fp32 [rows][1000] -> fp4 e2m1 [rows][1024] (zero padded)
__global__ __launch_bounds__(256) void conv_fp4_kernel(const float* __restrict__ src,
                                                       unsigned int* __restrict__ dst,
                                                       int nrows, float scale) {
  int t = blockIdx.x * 256 + threadIdx.x;
  int r = t >> 7;          // 128 uints (8 elems each) per row
  int c = t & 127;
  if (r >= nrows) return;
  unsigned int out = 0;
  if (c < 125) {           // 125*8 = 1000 exactly
    const float* p = src + (size_t)r * D + (c << 3);
    float4 v0 = *reinterpret_cast<const float4*>(p);
    float4 v1 = *reinterpret_cast<const float4*>(p + 4);
    out  = fp4nib(v0.x * scale);
    out |= fp4nib(v0.y * scale) << 4;
    out |= fp4nib(v0.z * scale) << 8;
    out |= fp4nib(v0.w * scale) << 12;
    out |= fp4nib(v1.x * scale) << 16;
    out |= fp4nib(v1.y * scale) << 20;
    out |= fp4nib(v1.z * scale) << 24;
    out |= fp4nib(v1.w * scale) << 28;
  }
  dst[(size_t)r * 128 + c] = out;
}

// fused: W fp32 -> fp4 (scaled) AND |w_k|^2 (from exact fp32). One wave per row.
__global__ __launch_bounds__(256) void conv_wnorm_kernel(const float* __restrict__ W,
                                                         unsigned int* __restrict__ dst,
                                                         float* __restrict__ wnorm) {
  const int tid = threadIdx.x;
  const int wv = tid >> 6;             // wave 0..3
  const int lane = tid & 63;
  const int r = blockIdx.x * 4 + wv;   // W row
  const float* p = W + (size_t)r * D;
  float s = 0.f;
  #pragma unroll
  for (int h = 0; h < 2; ++h) {
    const int c = lane + h * 64;       // uint chunk (8 elems)
    unsigned int out = 0;
    if (c < 125) {
      const float* q = p + (c << 3);
      float4 v0 = *reinterpret_cast<const float4*>(q);
      float4 v1 = *reinterpret_cast<const float4*>(q + 4);
      s += v0.x*v0.x + v0.y*v0.y + v0.z*v0.z + v0.w*v0.w
         + v1.x*v1.x + v1.y*v1.y + v1.z*v1.z + v1.w*v1.w;
      out  = fp4nib(v0.x * WSCALE4);
      out |= fp4nib(v0.y * WSCALE4) << 4;
      out |= fp4nib(v0.z * WSCALE4) << 8;
      out |= fp4nib(v0.w * WSCALE4) << 12;
      out |= fp4nib(v1.x * WSCALE4) << 16;
      out |= fp4nib(v1.y * WSCALE4) << 20;
      out |= fp4nib(v1.z * WSCALE4) << 24;
      out |= fp4nib(v1.w * WSCALE4) << 28;
    }
    dst[(size_t)r * 128 + c] = out;
  }
  #pragma unroll
  for (int off = 32; off; off >>= 1) s += __shfl_down(s, off);
  if (lane == 0) wnorm[r] = s;
}

// encodings = one_hot(label) + fused label histogram.
// Block = 2 rows (2048 float2); store j covers 256 contiguous float2 (2 KB/instr,
// row uniform per instruction -> label broadcast). 64 B/thread.
__global__ __launch_bounds__(256) void encodings_kernel(const int* __restrict__ label,
                                                        float2* __restrict__ enc,
                                                        unsigned int* __restrict__ counts) {
  const int tid = threadIdx.x;
  const size_t bb = (size_t)blockIdx.x * 2048;   // block's float2 base (2 rows)
  #pragma unroll
  for (int j = 0; j < 8; ++j) {
    const size_t fidx = bb + (size_t)j * 256 + tid;
    const int row = (int)(fidx >> 10);
    const int within = (int)(fidx & 1023);
    const int lab = label[row];
    float2 v = make_float2(0.f, 0.f);
    if ((lab >> 1) == within) {
      if (lab & 1) v.y = 1.f; else v.x = 1.f;
      atomicAdd(&counts[lab], 1u);               // exactly one hit per row
    }
    enc[fidx] = v;
  }
}

// Reoriented argmin: D = Wq4 . Xq4^T via MX-fp4 32x32x64 MFMA (FMT=4: e2m1).
// 3-buffer LDS, 2-deep prefetch, counted vmcnt(6). 512 thr / 8 waves,
// BM=256 codes x BN=128 samples; block covers 1024 codes (ct=0..3).
// Measured R11 diagnostic: 27.4 us/dispatch.
__global__ __launch_bounds__(512, 1) void argmin_kernel(const unsigned char* __restrict__ Xq,
                                                        const unsigned char* __restrict__ Wq,
                                                        const float* __restrict__ wnorm,
                                                        unsigned long long* __restrict__ best) {
  constexpr int BUFB = 49152;   // A 32 KB (256 rows x 128 B) + B 16 KB (128 x 128 B)
  __shared__ __attribute__((aligned(16))) unsigned char smem[151552];

  const int tid = threadIdx.x;
  const int bid = blockIdx.x;
  const int w = tid >> 6, l = tid & 63;
  const int wr = w >> 1;               // wave's code quarter of BM (0..3)
  const int wx = w & 1;                // wave's sample half (0,1)
  const int lc = l & 31;               // frag row / C-D col
  const int lh = l >> 5;               // k-half selector
  const int w0 = (bid & 1) * 1024;     // code-half base
  const int x0 = (bid >> 1) * 128;     // sample-panel base

  const int srow = tid >> 3;           // 0..63
  const int schunk = ((tid & 7) ^ (srow & 7)) << 4;
  auto lsm = (__attribute__((address_space(3))) unsigned char*)smem;
  const float* wsm = (const float*)(smem + 147456);

  const int sxo = lc & 7;
  int chv[4];
  #pragma unroll
  for (int tau = 0; tau < 4; ++tau) chv[tau] = (((2 * tau + lh) ^ sxo) << 4);
  int arow[2], brow[2];
  #pragma unroll
  for (int m = 0; m < 2; ++m) {
    arow[m] = (wr * 64 + m * 32 + lc) * 128;            // A: 256 rows x 128 B
    brow[m] = (wx * 64 + m * 32 + lc) * 128 + 32768;    // B: 128 rows x 128 B
  }

#define STAGE(Tn, _b) do {                                                               \
    const unsigned char* _gA = Wq + (size_t)(w0 + ((Tn) >> 2) * 256 + srow) * RB         \
                               + ((Tn) & 3) * 128 + schunk;                              \
    const unsigned char* _gB = Xq + (size_t)(x0 + srow) * RB                             \
                               + ((Tn) & 3) * 128 + schunk;                              \
    _Pragma("unroll")                                                                    \
    for (int _i = 0; _i < 4; ++_i)                                                       \
      __builtin_amdgcn_global_load_lds((gp_t)(_gA + (size_t)(64 * _i) * RB),             \
                                       (lp_t)(lsm + (_b) + _i * 8192 + tid * 16), 16, 0, 0);\
    _Pragma("unroll")                                                                    \
    for (int _i = 0; _i < 2; ++_i)                                                       \
      __builtin_amdgcn_global_load_lds((gp_t)(_gB + (size_t)(64 * _i) * RB),             \
                                       (lp_t)(lsm + (_b) + 32768 + _i * 8192 + tid * 16), 16, 0, 0);\
  } while (0)

#define KBODY(bufb) do {                                                                 \
    _Pragma("unroll")                                                                    \
    for (int tau = 0; tau < 4; ++tau) {                                                  \
      int4v la0 = *reinterpret_cast<const int4v*>(smem + (bufb) + arow[0] + chv[tau]);   \
      int4v la1 = *reinterpret_cast<const int4v*>(smem + (bufb) + arow[1] + chv[tau]);   \
      int4v lb0 = *reinterpret_cast<const int4v*>(smem + (bufb) + brow[0] + chv[tau]);   \
      int4v lb1 = *reinterpret_cast<const int4v*>(smem + (bufb) + brow[1] + chv[tau]);   \
      int8v a0, a1, b0, b1;                                                              \
      a0[0]=la0[0];a0[1]=la0[1];a0[2]=la0[2];a0[3]=la0[3];                               \
      a0[4]=la0[0];a0[5]=la0[1];a0[6]=la0[2];a0[7]=la0[3];                               \
      a1[0]=la1[0];a1[1]=la1[1];a1[2]=la1[2];a1[3]=la1[3];                               \
      a1[4]=la1[0];a1[5]=la1[1];a1[6]=la1[2];a1[7]=la1[3];                               \
      b0[0]=lb0[0];b0[1]=lb0[1];b0[2]=lb0[2];b0[3]=lb0[3];                               \
      b0[4]=lb0[0];b0[5]=lb0[1];b0[6]=lb0[2];b0[7]=lb0[3];                               \
      b1[0]=lb1[0];b1[1]=lb1[1];b1[2]=lb1[2];b1[3]=lb1[3];                               \
      b1[4]=lb1[0];b1[5]=lb1[1];b1[6]=lb1[2];b1[7]=lb1[3];                               \
      __builtin_amdgcn_s_setprio(1);                                                     \
      acc[0][0] = __builtin_amdgcn_mfma_scale_f32_32x32x64_f8f6f4(a0, b0, acc[0][0], 4, 4, 0, 0x7f7f7f7f, 0, 0x7f7f7f7f); \
      acc[0][1] = __builtin_amdgcn_mfma_scale_f32_32x32x64_f8f6f4(a0, b1, acc[0][1], 4, 4, 0, 0x7f7f7f7f, 0, 0x7f7f7f7f); \
      acc[1][0] = __builtin_amdgcn_mfma_scale_f32_32x32x64_f8f6f4(a1, b0, acc[1][0], 4, 4, 0, 0x7f7f7f7f, 0, 0x7f7f7f7f); \
      acc[1][1] = __builtin_amdgcn_mfma_scale_f32_32x32x64_f8f6f4(a1, b1, acc[1][1], 4, 4, 0, 0x7f7f7f7f, 0, 0x7f7f7f7f); \
      __builtin_amdgcn_s_setprio(0);                                                     \
    }                                                                                    \
  } while (0)

#define FOLD(ct_) do {                                                                   \
    _Pragma("unroll")                                                                    \
    for (int m = 0; m < 2; ++m) {                                                        \
      _Pragma("unroll")                                                                  \
      for (int r = 0; r < 16; ++r) {                                                     \
        const int wl = wr * 64 + m * 32 + (r & 3) + 8 * (r >> 2) + 4 * lh;               \
        const float wn = wsm[(ct_) * 256 + wl];                                          \
        const unsigned int nw = ~(unsigned int)(w0 + (ct_) * 256 + wl);                  \
        float s0 = dsc * acc[m][0][r] - wn;                                              \
        float s1 = dsc * acc[m][1][r] - wn;                                              \
        unsigned int u0 = __float_as_uint(s0);                                           \
        u0 = (u0 & 0x80000000u) ? ~u0 : (u0 | 0x80000000u);                              \
        unsigned int u1 = __float_as_uint(s1);                                           \
        u1 = (u1 & 0x80000000u) ? ~u1 : (u1 | 0x80000000u);                              \
        unsigned long long p0 = ((unsigned long long)u0 << 32) | nw;                     \
        unsigned long long p1 = ((unsigned long long)u1 << 32) | nw;                     \
        if (p0 > best0) best0 = p0;                                                      \
        if (p1 > best1) best1 = p1;                                                      \
        acc[m][0][r] = 0.f;                                                              \
        acc[m][1][r] = 0.f;                                                              \
      }                                                                                  \
    }                                                                                    \
  } while (0)

  f32x16 acc[2][2];
  #pragma unroll
  for (int m = 0; m < 2; ++m)
    #pragma unroll
    for (int n = 0; n < 2; ++n)
      #pragma unroll
      for (int r = 0; r < 16; ++r) acc[m][n][r] = 0.f;

  const float dsc = 2.0f / WSCALE4;
  unsigned long long best0 = 0ull, best1 = 0ull;

  // prologue: wsm (2 loads FIRST so step-0's vmcnt(6) covers them), then T=0, T=1
  __builtin_amdgcn_global_load_lds((gp_t)(wnorm + w0 + tid),
                                   (lp_t)(lsm + 147456 + tid * 4), 4, 0, 0);
  __builtin_amdgcn_global_load_lds((gp_t)(wnorm + w0 + 512 + tid),
                                   (lp_t)(lsm + 147456 + 2048 + tid * 4), 4, 0, 0);
  STAGE(0, 0);
  STAGE(1, BUFB);

  int bufb = 0;            // buffer of macro-step T
  int sb = 2 * BUFB;       // buffer for STAGE(T+2)
  for (int T = 0; T < 15; ++T) {
    asm volatile("s_waitcnt vmcnt(6)" ::: "memory");
    __builtin_amdgcn_s_barrier();                     // all waves' stage(T) landed
    __builtin_amdgcn_sched_barrier(0);                // nothing crosses the barrier
    if (T + 2 < 16) STAGE(T + 2, sb);                 // overwrites buf(T-1): readers passed barrier
    KBODY(bufb);
    if ((T & 3) == 3) FOLD(T >> 2);
    bufb = (bufb == 2 * BUFB) ? 0 : bufb + BUFB;
    sb = (sb == 2 * BUFB) ? 0 : sb + BUFB;
  }
  {  // peeled last macro-step: drain fully
    asm volatile("s_waitcnt vmcnt(0)" ::: "memory");
    __builtin_amdgcn_s_barrier();
    __builtin_amdgcn_sched_barrier(0);
    KBODY(bufb);
    FOLD(3);
  }
#undef STAGE
#undef KBODY
#undef FOLD

  // merge lane-halves (same sample, different code rows), one atomic per sample
  unsigned long long o0 = __shfl_xor(best0, 32);
  if (o0 > best0) best0 = o0;
  unsigned long long o1 = __shfl_xor(best1, 32);
  if (o1 > best1) best1 = o1;
  if (lh == 0) {
    atomicMax(best + x0 + wx * 64 + lc, best0);
    atomicMax(best + x0 + wx * 64 + 32 + lc, best1);
  }
}

// gather quantized rows, write straight-through output, per-block partial sums (NO atomics)
__global__ __launch_bounds__(256) void gather_loss_kernel(const float* __restrict__ X,
                                                          const float* __restrict__ W,
                                                          const int* __restrict__ label,
                                                          const unsigned long long* __restrict__ best,
                                                          float* __restrict__ outq,
                                                          float* __restrict__ partials) {
  const int tid = threadIdx.x;
  float qs = 0.f, xs = 0.f;
  #pragma unroll
  for (int i = 0; i < 8; ++i) {
    const int r = blockIdx.x * 8 + i;
    const int lab = label[r];
    const int k = (int)(~(unsigned int)(best[r] & 0xffffffffull));
    const float ind = (lab != k) ? 1.0f : 0.0f;
    if (tid < 250) {
      const float4 x4 = reinterpret_cast<const float4*>(X + (size_t)r * D)[tid];
      const float4 q4 = reinterpret_cast<const float4*>(W + (size_t)lab * D)[tid];
      const float4 c4 = reinterpret_cast<const float4*>(W + (size_t)k * D)[tid];
      float* orow = outq + (size_t)r * D + tid * 4;
      orow[0] = x4.x + (q4.x - x4.x);
      orow[1] = x4.y + (q4.y - x4.y);
      orow[2] = x4.z + (q4.z - x4.z);
      orow[3] = x4.w + (q4.w - x4.w);
      float dq, dc, rx = 0.f, rq = 0.f;
      dq = q4.x - x4.x; rq += dq * dq;  dq = q4.y - x4.y; rq += dq * dq;
      dq = q4.z - x4.z; rq += dq * dq;  dq = q4.w - x4.w; rq += dq * dq;
      dc = c4.x - x4.x; rx += dc * dc;  dc = c4.y - x4.y; rx += dc * dc;
      dc = c4.z - x4.z; rx += dc * dc;  dc = c4.w - x4.w; rx += dc * dc;
      qs += rq;
      xs += ind * rx;
    }
  }
  #pragma unroll
  for (int off = 32; off; off >>= 1) {
    qs += __shfl_down(qs, off);
    xs += __shfl_down(xs, off);
  }
  __shared__ float sq[4], sx[4];
  if ((tid & 63) == 0) { sq[tid >> 6] = qs; sx[tid >> 6] = xs; }
  __syncthreads();
  if (tid == 0) {
    partials[blockIdx.x * 2 + 0] = sq[0] + sq[1] + sq[2] + sq[3];
    partials[blockIdx.x * 2 + 1] = sx[0] + sx[1] + sx[2] + sx[3];
  }
}

__global__ __launch_bounds__(256) void final_kernel(const unsigned int* __restrict__ counts,
                                                    const float* __restrict__ partials,
                                                    float* __restrict__ out) {
  const int tid = threadIdx.x;
  float e = 0.f, qs = 0.f, xs = 0.f;
  for (int k = tid; k < K; k += 256) {
    float p = (float)counts[k] * (1.0f / (float)N);
    e += p * logf(p + 1e-10f);
  }
  for (int i = tid; i < 2048; i += 256) {
    qs += partials[i * 2 + 0];
    xs += partials[i * 2 + 1];
  }
  #pragma unroll
  for (int off = 32; off; off >>= 1) {
    e += __shfl_down(e, off);
    qs += __shfl_down(qs, off);
    xs += __shfl_down(xs, off);
  }
  __shared__ float se[4], ssq[4], ssx[4];
  if ((tid & 63) == 0) { se[tid >> 6] = e; ssq[tid >> 6] = qs; ssx[tid >> 6] = xs; }
  __syncthreads();
  if (tid == 0) {
    float ent = se[0] + se[1] + se[2] + se[3];
    float q = ssq[0] + ssq[1] + ssq[2] + ssq[3];
    float x = ssx[0] + ssx[1] + ssx[2] + ssx[3];
    const float inv = 1.0f / (float)((long long)N * D);
    out[0] = 1.25f * q * inv - 1.1f * x * inv;   // loss
    out[1 + ND] = expf(-ent);                    // perplexity
  }
}

extern "C" void kernel_launch(void* const* d_in, const int* in_sizes, int n_in,
                              void* d_out, int out_size, void* d_ws, size_t ws_size,
                              hipStream_t stream) {
  const float* X = (const float*)d_in[0];
  const int* label = (const int*)d_in[1];
  const float* W = (const float*)d_in[2];
  float* out = (float*)d_out;
  char* ws = (char*)d_ws;

  unsigned long long* best = (unsigned long long*)(ws + OFF_BEST);
  unsigned int* counts = (unsigned int*)(ws + OFF_COUNTS);
  float* partials = (float*)(ws + OFF_PART);
  unsigned char* Xq = (unsigned char*)(ws + OFF_XQ);
  unsigned char* Wq = (unsigned char*)(ws + OFF_WQ);
  float* wnorm = (float*)(ws + OFF_WNORM);

  init_kernel<<<34, 256, 0, stream>>>((uint4*)ws);   // zero best+counts (139264 B)

  conv_fp4_kernel<<<(N * 128) / 256, 256, 0, stream>>>(X, (unsigned int*)Xq, N, 1.0f);
  conv_wnorm_kernel<<<K / 4, 256, 0, stream>>>(W, (unsigned int*)Wq, wnorm);
  encodings_kernel<<<N / 2, 256, 0, stream>>>(label, (float2*)(out + 2 + ND), counts);
  argmin_kernel<<<256, 512, 0, stream>>>(Xq, Wq, wnorm, best);
  gather_loss_kernel<<<N / 8, 256, 0, stream>>>(X, W, label, best, out + 1, partials);
  final_kernel<<<1, 256, 0, stream>>>(counts, partials, out);
}